// Round 20
// baseline (249.951 us; speedup 1.0000x reference)
//
#include <hip/hip_runtime.h>

#define SEQ 2048
#define BB 4
#define DM 1024
#define NH 16
#define DH 64
#define ROWS (BB*SEQ)

#define BM 128
#define BN 128
#define BK 32
#define KSTEPS (DM / BK)

#define KVBLK 64
#define NT (SEQ / KVBLK)
#define NBUF 3

typedef _Float16 f16;
typedef _Float16 f16x8 __attribute__((ext_vector_type(8)));
typedef _Float16 f16x4 __attribute__((ext_vector_type(4)));
typedef __fp16 h2 __attribute__((ext_vector_type(2)));
typedef float f32x4 __attribute__((ext_vector_type(4)));
typedef float f32x16 __attribute__((ext_vector_type(16)));
typedef unsigned u32x4 __attribute__((ext_vector_type(4)));

__device__ __forceinline__ f32x4 mfma16(f16x8 a, f16x8 b, f32x4 c) {
    return __builtin_amdgcn_mfma_f32_16x16x32_f16(a, b, c, 0, 0, 0);
}
__device__ __forceinline__ f32x16 mfma32(f16x8 a, f16x8 b, f32x16 c) {
    return __builtin_amdgcn_mfma_f32_32x32x16_f16(a, b, c, 0, 0, 0);
}
__device__ __forceinline__ unsigned pkh(float a, float b) {
    auto h = __builtin_amdgcn_cvt_pkrtz(a, b);   // __fp16 ext_vector(2)
    return __builtin_bit_cast(unsigned, h);
}
// v_dot2_f32_f16: acc += w.x*1 + w.y*1  (sums a packed f16 pair into f32)
__device__ __forceinline__ float sum2(unsigned w, float acc) {
    h2 one = { (__fp16)1.0f, (__fp16)1.0f };
    return __builtin_amdgcn_fdot2(__builtin_bit_cast(h2, w), one, acc, false);
}
// v_permlane32_swap_b32 (vdst=a, vsrc=b):
//   new_a = {lo: a.lo, hi: b.lo};  new_b = {lo: a.hi, hi: b.hi}
__device__ __forceinline__ void plswap(unsigned& a, unsigned& b) {
    auto r = __builtin_amdgcn_permlane32_swap((int)a, (int)b, false, false);
    a = (unsigned)r[0];
    b = (unsigned)r[1];
}
__device__ __forceinline__ float2 plswapf(float x) {
    int xi = __builtin_bit_cast(int, x);
    auto r = __builtin_amdgcn_permlane32_swap(xi, xi, false, false);
    return float2{ __builtin_bit_cast(float, (int)r[0]), __builtin_bit_cast(float, (int)r[1]) };
}
// async global->LDS, 16B per lane; LDS dest = wave-uniform base + lane*16
typedef const __attribute__((address_space(1))) void gvoid;
typedef __attribute__((address_space(3))) void lvoid;
__device__ __forceinline__ void gload16(const f16* g, f16* l) {
    __builtin_amdgcn_global_load_lds((gvoid*)g, (lvoid*)l, 16, 0, 0);
}

// ---------------- weight conversion fp32 -> f16 (+ mask pack in block 0) -------
__global__ __launch_bounds__(256) void cvt_weights(
    const float* __restrict__ wq, const float* __restrict__ wk,
    const float* __restrict__ wv, const float* __restrict__ wo,
    f16* __restrict__ oq, f16* __restrict__ ok,
    f16* __restrict__ ov, f16* __restrict__ oo,
    const int* __restrict__ mask, unsigned* __restrict__ pm) {
    if (blockIdx.x == 0) {
        int tid = threadIdx.x;      // 0..255, packs 32 mask ints each
        const int* mp = mask + (size_t)tid * 32;
        unsigned bits = 0;
#pragma unroll
        for (int j = 0; j < 32; ++j) bits |= (mp[j] != 0 ? 1u : 0u) << j;
        pm[tid] = bits;
    }
    int i = (blockIdx.x * 256 + threadIdx.x) * 4;
    float4 a = *(const float4*)(wq + i);
    float4 b = *(const float4*)(wk + i);
    float4 c = *(const float4*)(wv + i);
    float4 d = *(const float4*)(wo + i);
    f16x4 va = { (f16)a.x, (f16)a.y, (f16)a.z, (f16)a.w };
    f16x4 vb = { (f16)b.x, (f16)b.y, (f16)b.z, (f16)b.w };
    f16x4 vc = { (f16)c.x, (f16)c.y, (f16)c.z, (f16)c.w };
    f16x4 vd = { (f16)d.x, (f16)d.y, (f16)d.z, (f16)d.w };
    *(f16x4*)(oq + i) = va;
    *(f16x4*)(ok + i) = vb;
    *(f16x4*)(ov + i) = vc;
    *(f16x4*)(oo + i) = vd;
}

// ---------------- fused 3-way QKV projection GEMM (A fp32, cvt in-kernel) ------
// grid (ROWS/BM, DM/BN, 3): z selects {Q,K,V} projection.
// lds_b: slot s of row R holds col-block s ^ ((R>>1)&3) (within-row XOR swizzle;
// global source pre-permuted, LDS dest linear, read uses matching index ->
// B-fragment ds_read_b128 is 2-way max (free) instead of 8-way).
__global__ __launch_bounds__(256) void gemm_proj3(
    const float* __restrict__ Qf, const float* __restrict__ Kf,
    const float* __restrict__ Vf,
    const f16* __restrict__ wq, const f16* __restrict__ wk,
    const f16* __restrict__ wv,
    const float* __restrict__ bq, const float* __restrict__ bk,
    const float* __restrict__ bv,
    f16* __restrict__ q16o, f16* __restrict__ k16o, f16* __restrict__ v16o,
    float qscale) {
    const float* A; const f16* W; const float* bias; f16* out;
    float scale; int mode;
    if (blockIdx.z == 0)      { A = Qf; W = wq; bias = bq; out = q16o; scale = qscale; mode = 0; }
    else if (blockIdx.z == 1) { A = Kf; W = wk; bias = bk; out = k16o; scale = 1.0f;   mode = 0; }
    else                      { A = Vf; W = wv; bias = bv; out = v16o; scale = 1.0f;   mode = 2; }

    __shared__ f16 lds_a[2][BM][BK + 8];   // reg-staged, padded (2-way max)
    __shared__ f16 lds_b[2][BN][BK];       // gload16-staged, XOR-swizzled
    const int tid = threadIdx.x;
    const int lane = tid & 63;
    const int wv_ = tid >> 6;
    const int wr = wv_ >> 1, wc = wv_ & 1;
    const int lo = lane & 15, hi = lane >> 4;
    const int rowbase = blockIdx.x * BM;
    const int colbase = blockIdx.y * BN;
    const int ar = tid >> 1;            // A row 0..127
    const int ac = (tid & 1) * 16;      // A col half

    f32x4 acc[4][4];
#pragma unroll
    for (int m = 0; m < 4; ++m)
#pragma unroll
        for (int n = 0; n < 4; ++n) acc[m][n] = (f32x4){0.f, 0.f, 0.f, 0.f};

    float4 av0, av1, av2, av3;
#define LOAD_A(k0)                                                                  \
    {                                                                               \
        const float* ap_ = A + (size_t)(rowbase + ar) * DM + (k0) + ac;             \
        av0 = *(const float4*)(ap_);                                                \
        av1 = *(const float4*)(ap_ + 4);                                            \
        av2 = *(const float4*)(ap_ + 8);                                            \
        av3 = *(const float4*)(ap_ + 12);                                           \
    }
#define WRITE_A(buf)                                                                \
    {                                                                               \
        f16* dp_ = &lds_a[buf][ar][ac];                                             \
        u32x4 t0_ = { pkh(av0.x, av0.y), pkh(av0.z, av0.w),                         \
                      pkh(av1.x, av1.y), pkh(av1.z, av1.w) };                       \
        u32x4 t1_ = { pkh(av2.x, av2.y), pkh(av2.z, av2.w),                         \
                      pkh(av3.x, av3.y), pkh(av3.z, av3.w) };                       \
        *(u32x4*)(dp_) = t0_;                                                       \
        *(u32x4*)(dp_ + 8) = t1_;                                                   \
    }
// lane -> row r_ (=lane>>2, row-within-16-chunk), slot lane&3; source col-block
// is (lane&3)^((r_>>1)&3) so that slot s holds block s^((R>>1)&3).
#define STAGE_W(buf, k0)                                                            \
    {                                                                               \
        int r_ = lane >> 2;                                                         \
        int kc_ = (((lane & 3) ^ ((r_ >> 1) & 3))) * 8;                             \
        gload16(W + (size_t)(colbase + wv_ * 16 + r_) * DM + (k0) + kc_,            \
                &lds_b[buf][wv_ * 16][0]);                                          \
        gload16(W + (size_t)(colbase + (wv_ + 4) * 16 + r_) * DM + (k0) + kc_,      \
                &lds_b[buf][(wv_ + 4) * 16][0]);                                    \
    }

    LOAD_A(0)
    STAGE_W(0, 0)
    WRITE_A(0)
    __syncthreads();
    int buf = 0;
    for (int ks = 0; ks < KSTEPS; ++ks) {
        if (ks + 1 < KSTEPS) {
            LOAD_A((ks + 1) * BK)
            STAGE_W(buf ^ 1, (ks + 1) * BK)
        }
        f16x8 af[4], bf[4];
#pragma unroll
        for (int m = 0; m < 4; ++m)
            af[m] = *(const f16x8*)&lds_a[buf][wr * 64 + m * 16 + lo][hi * 8];
#pragma unroll
        for (int n = 0; n < 4; ++n) {
            int Rn = wc * 64 + n * 16 + lo;
            bf[n] = *(const f16x8*)&lds_b[buf][Rn][(hi ^ ((Rn >> 1) & 3)) * 8];
        }
#pragma unroll
        for (int m = 0; m < 4; ++m)
#pragma unroll
            for (int n = 0; n < 4; ++n)
                acc[m][n] = mfma16(af[m], bf[n], acc[m][n]);
        if (ks + 1 < KSTEPS) WRITE_A(buf ^ 1)     // vm-wait lands after MFMAs
        __syncthreads();
        buf ^= 1;
    }
#undef LOAD_A
#undef WRITE_A
#undef STAGE_W

#pragma unroll
    for (int n = 0; n < 4; ++n) {
        int col = colbase + wc * 64 + n * 16 + lo;
        float bv_ = bias[col];
        int hh = col >> 6, dh = col & 63;
#pragma unroll
        for (int m = 0; m < 4; ++m)
#pragma unroll
            for (int r = 0; r < 4; ++r) {
                int row = rowbase + wr * 64 + m * 16 + hi * 4 + r;
                int bi = row >> 11;
                int ss = row & (SEQ - 1);
                float v = (acc[m][n][r] + bv_) * scale;
                size_t dst;
                if (mode == 2)
                    dst = (((size_t)(bi * NH + hh) * DH + dh) * SEQ + ss);
                else
                    dst = (((size_t)(bi * NH + hh) * SEQ + ss) * DH + dh);
                out[dst] = (f16)v;
            }
    }
}

// ---------------- GEMM, output projection + bias + residual (swizzled LDS) -----
__global__ __launch_bounds__(256) void gemm_oproj(
    const f16* __restrict__ A, const f16* __restrict__ W,
    const float* __restrict__ bo, const float* __restrict__ Qin,
    float* __restrict__ out) {
    __shared__ f16 lds_a[2][BM][BK];
    __shared__ f16 lds_b[2][BN][BK];
    const int lane = threadIdx.x & 63;
    const int wv = threadIdx.x >> 6;
    const int wr = wv >> 1, wc = wv & 1;
    const int lo = lane & 15, hi = lane >> 4;
    const int rowbase = blockIdx.x * BM;
    const int colbase = blockIdx.y * BN;

    f32x4 acc[4][4];
#pragma unroll
    for (int m = 0; m < 4; ++m)
#pragma unroll
        for (int n = 0; n < 4; ++n) acc[m][n] = (f32x4){0.f, 0.f, 0.f, 0.f};

#define STAGE_TILES(buf, k0)                                                        \
    {                                                                               \
        int r_ = lane >> 2;                                                         \
        int kc_ = (((lane & 3) ^ ((r_ >> 1) & 3))) * 8;                             \
        gload16(A + (size_t)(rowbase + wv * 16 + r_) * DM + (k0) + kc_,             \
                &lds_a[buf][wv * 16][0]);                                           \
        gload16(A + (size_t)(rowbase + (wv + 4) * 16 + r_) * DM + (k0) + kc_,       \
                &lds_a[buf][(wv + 4) * 16][0]);                                     \
        gload16(W + (size_t)(colbase + wv * 16 + r_) * DM + (k0) + kc_,             \
                &lds_b[buf][wv * 16][0]);                                           \
        gload16(W + (size_t)(colbase + (wv + 4) * 16 + r_) * DM + (k0) + kc_,       \
                &lds_b[buf][(wv + 4) * 16][0]);                                     \
    }

    STAGE_TILES(0, 0)
    __syncthreads();
    int buf = 0;
    for (int ks = 0; ks < KSTEPS; ++ks) {
        if (ks + 1 < KSTEPS) STAGE_TILES(buf ^ 1, (ks + 1) * BK)
        f16x8 af[4], bf[4];
#pragma unroll
        for (int m = 0; m < 4; ++m) {
            int Rm = wr * 64 + m * 16 + lo;
            af[m] = *(const f16x8*)&lds_a[buf][Rm][(hi ^ ((Rm >> 1) & 3)) * 8];
        }
#pragma unroll
        for (int n = 0; n < 4; ++n) {
            int Rn = wc * 64 + n * 16 + lo;
            bf[n] = *(const f16x8*)&lds_b[buf][Rn][(hi ^ ((Rn >> 1) & 3)) * 8];
        }
#pragma unroll
        for (int m = 0; m < 4; ++m)
#pragma unroll
            for (int n = 0; n < 4; ++n)
                acc[m][n] = mfma16(af[m], bf[n], acc[m][n]);
        __syncthreads();
        buf ^= 1;
    }
#undef STAGE_TILES

#pragma unroll
    for (int n = 0; n < 4; ++n) {
        int col = colbase + wc * 64 + n * 16 + lo;
        float bv = bo[col];
#pragma unroll
        for (int m = 0; m < 4; ++m)
#pragma unroll
            for (int r = 0; r < 4; ++r) {
                int row = rowbase + wr * 64 + m * 16 + hi * 4 + r;
                size_t idx = (size_t)row * DM + col;
                out[idx] = acc[m][n][r] + bv + Qin[idx];
            }
    }
}

// ---------------- fused flash attention: 64-key tiles, 1 barrier per tile ------
// grid: (SEQ/128, BB*NH), block 256 (4 waves x 32 q-rows). LDS 48 KB (3 bufs).
// Fixed-shift softmax (C=0), raw v_exp_f32, l via dot2, l-reduce deferred.
__global__ __launch_bounds__(256, 3) void attn_kernel(
    const f16* __restrict__ q16, const f16* __restrict__ k16,
    const f16* __restrict__ v16t, const unsigned* __restrict__ pm,
    f16* __restrict__ out16) {
    __shared__ f16 smem[NBUF][2][KVBLK * 64];    // [buf][K/V][4096 f16] = 48 KB
    const int tid = threadIdx.x;
    const int lane = tid & 63;
    const int wv = tid >> 6;
    const int lo = lane & 31, hw = lane >> 5;
    const int bh = blockIdx.y;
    const int b = bh >> 4, hd = bh & 15;
    const int q0 = blockIdx.x * 128 + wv * 32;

    const f16* qp = q16 + ((size_t)bh * SEQ + q0 + lo) * DH + hw * 8;
    const f16* kp = k16 + (size_t)bh * SEQ * DH;
    const f16* vp = v16t + (size_t)bh * DH * SEQ;
    const unsigned* pmb = pm + b * 64;

    // staging: 8 lanes/row; rows [wv*8, wv*8+8) and [32+wv*8, 32+wv*8+8)
    const int sr = lane >> 3, scb = lane & 7;
    const int cb = scb ^ sr;               // col-block loaded into slot scb

    f16x8 qb[4];
#pragma unroll
    for (int c = 0; c < 4; ++c) qb[c] = *(const f16x8*)(qp + c * 16);

    f32x16 fz;
#pragma unroll
    for (int i = 0; i < 16; ++i) fz[i] = 0.f;
    f32x16 ctx0 = fz, ctx1 = fz;
    float la = 0.f, lb = 0.f;    // own-half partial l (dot2-accumulated)

    // 4 gload16 per wave per STAGE; K tile [64 keys][64 dh], V^T tile [64 dh][64 k]
#define STAGE(buf, KB)                                                              \
    {                                                                               \
        gload16(kp + (size_t)((KB) + wv * 8 + sr) * DH + cb * 8,                    \
                &smem[buf][0][wv * 512]);                                           \
        gload16(kp + (size_t)((KB) + 32 + wv * 8 + sr) * DH + cb * 8,               \
                &smem[buf][0][(4 + wv) * 512]);                                     \
        gload16(vp + (size_t)(wv * 8 + sr) * SEQ + (KB) + cb * 8,                   \
                &smem[buf][1][wv * 512]);                                           \
        gload16(vp + (size_t)(32 + wv * 8 + sr) * SEQ + (KB) + cb * 8,              \
                &smem[buf][1][(4 + wv) * 512]);                                     \
    }

    STAGE(0, 0)
    STAGE(1, KVBLK)

    int bc = 0;                       // t % NBUF
    for (int t = 0; t < NT; ++t) {
        // counted wait: own STAGE(t) (4 loads) landed; STAGE(t+1) may stay in flight
        if (t < NT - 1) asm volatile("s_waitcnt vmcnt(4)" ::: "memory");
        else            asm volatile("s_waitcnt vmcnt(0)" ::: "memory");
        __builtin_amdgcn_s_barrier();
        asm volatile("" ::: "memory");

        const f16* kbase = &smem[bc][0][0];
        const f16* vbase = &smem[bc][1][0];

        // ---- prefetch 2 tiles ahead (into buffer last read at tile t-1) ----
        if (t + 2 < NT) {
            int bs = bc + 2; if (bs >= NBUF) bs -= NBUF;
            STAGE(bs, (t + 2) * KVBLK)
        }

        unsigned bmw0 = pmb[2 * t];
        unsigned bmw1 = pmb[2 * t + 1];

#pragma unroll
        for (int kt = 0; kt < 2; ++kt) {
            // ---- K fragments: row kt*32+lo, d-slot (2c+hw)^(lo&7) ----
            f16x8 kf0 = *(const f16x8*)&kbase[(kt * 32 + lo) * 64 + (((0 + hw) ^ (lo & 7)) << 3)];
            f16x8 kf1 = *(const f16x8*)&kbase[(kt * 32 + lo) * 64 + (((2 + hw) ^ (lo & 7)) << 3)];

            f32x16 st;
            __builtin_amdgcn_s_setprio(1);
            st = mfma32(kf0, qb[0], fz);
            f16x8 kf2 = *(const f16x8*)&kbase[(kt * 32 + lo) * 64 + (((4 + hw) ^ (lo & 7)) << 3)];
            st = mfma32(kf1, qb[1], st);
            f16x8 kf3 = *(const f16x8*)&kbase[(kt * 32 + lo) * 64 + (((6 + hw) ^ (lo & 7)) << 3)];
            st = mfma32(kf2, qb[2], st);
            st = mfma32(kf3, qb[3], st);
            __builtin_amdgcn_s_setprio(0);

            // ---- mask (packed bits) ----
            unsigned bm = kt ? bmw1 : bmw0;
            if (bm != 0xffffffffu) {
                unsigned bs_ = bm >> (hw * 4);
#pragma unroll
                for (int r = 0; r < 16; ++r)
                    if (!((bs_ >> ((r & 3) + 8 * (r >> 2))) & 1)) st[r] = -1e9f;
            }

            // ---- P = exp2(s) (raw v_exp_f32) ----
#pragma unroll
            for (int i = 0; i < 16; ++i) st[i] = __builtin_amdgcn_exp2f(st[i]);

            // ---- pack, l via dot2, vf reads, PV MFMAs ----
            __builtin_amdgcn_s_setprio(1);
            {
                unsigned w0 = pkh(st[0], st[1]),   w1 = pkh(st[2], st[3]);
                unsigned w2 = pkh(st[4], st[5]),   w3 = pkh(st[6], st[7]);
                unsigned w4 = pkh(st[8], st[9]),   w5 = pkh(st[10], st[11]);
                unsigned w6 = pkh(st[12], st[13]), w7 = pkh(st[14], st[15]);
                la = sum2(w0, la); lb = sum2(w1, lb);
                la = sum2(w2, la); lb = sum2(w3, lb);
                la = sum2(w4, la); lb = sum2(w5, lb);
                la = sum2(w6, la); lb = sum2(w7, lb);
                f16x8 vf00 = *(const f16x8*)&vbase[(0 * 32 + lo) * 64 + (((kt * 4 + 0 + hw) ^ (lo & 7)) << 3)];
                f16x8 vf10 = *(const f16x8*)&vbase[(1 * 32 + lo) * 64 + (((kt * 4 + 0 + hw) ^ (lo & 7)) << 3)];
                {
                    unsigned a0 = w0, b0 = w2; plswap(a0, b0);
                    unsigned a1 = w1, b1 = w3; plswap(a1, b1);
                    u32x4 t_ = { a0, a1, b0, b1 };
                    f16x8 pb = __builtin_bit_cast(f16x8, t_);
                    ctx0 = mfma32(vf00, pb, ctx0);
                    ctx1 = mfma32(vf10, pb, ctx1);
                }
                f16x8 vf01 = *(const f16x8*)&vbase[(0 * 32 + lo) * 64 + (((kt * 4 + 2 + hw) ^ (lo & 7)) << 3)];
                f16x8 vf11 = *(const f16x8*)&vbase[(1 * 32 + lo) * 64 + (((kt * 4 + 2 + hw) ^ (lo & 7)) << 3)];
                {
                    unsigned a0 = w4, b0 = w6; plswap(a0, b0);
                    unsigned a1 = w5, b1 = w7; plswap(a1, b1);
                    u32x4 t_ = { a0, a1, b0, b1 };
                    f16x8 pb = __builtin_bit_cast(f16x8, t_);
                    ctx0 = mfma32(vf01, pb, ctx0);
                    ctx1 = mfma32(vf11, pb, ctx1);
                }
            }
            __builtin_amdgcn_s_setprio(0);
        }

        bc = (bc + 1 == NBUF) ? 0 : bc + 1;
    }
#undef STAGE

    __syncthreads();   // all waves done with smem tiles before transpose reuse

    // ---- epilogue: combine l halves (deferred), divide, transpose, store ----
    float lown = la + lb;
    float2 lp = plswapf(lown);
    float rl = 1.0f / (lp.x + lp.y);
    f16* tbp = &smem[0][0][0] + wv * (32 * 66);
#pragma unroll
    for (int u = 0; u < 8; ++u) {
        int d0 = 2 * (u & 1) + 8 * (u >> 1) + 4 * hw;
        unsigned pw0 = pkh(ctx0[2 * u] * rl, ctx0[2 * u + 1] * rl);
        unsigned pw1 = pkh(ctx1[2 * u] * rl, ctx1[2 * u + 1] * rl);
        *(unsigned*)&tbp[lo * 66 + d0] = pw0;
        *(unsigned*)&tbp[lo * 66 + 32 + d0] = pw1;
    }
    __syncthreads();
#pragma unroll
    for (int it = 0; it < 4; ++it) {
        int r = it * 8 + (lane >> 3);
        const unsigned* src = (const unsigned*)(tbp + r * 66);
        int cc = (lane & 7) * 4;
        u32x4 t = { src[cc], src[cc + 1], src[cc + 2], src[cc + 3] };
        f16x8 vvv = __builtin_bit_cast(f16x8, t);
        *(f16x8*)(out16 + ((size_t)(b * SEQ) + q0 + r) * DM + hd * 64 + (lane & 7) * 8) = vvv;
    }
}

// ---------------- in-place LayerNorm ----------------
__global__ __launch_bounds__(256) void ln_kernel(
    float* __restrict__ x, const float* __restrict__ gamma,
    const float* __restrict__ beta) {
    const int lane = threadIdx.x & 63;
    const int wave = threadIdx.x >> 6;
    const int row = blockIdx.x * 4 + wave;
    float* rp = x + (size_t)row * DM;

    float4 v[4];
#pragma unroll
    for (int j = 0; j < 4; ++j) v[j] = ((const float4*)rp)[lane + 64 * j];

    float sum = 0.f;
#pragma unroll
    for (int j = 0; j < 4; ++j) sum += v[j].x + v[j].y + v[j].z + v[j].w;
#pragma unroll
    for (int off = 1; off < 64; off <<= 1) sum += __shfl_xor(sum, off);
    float mean = sum * (1.f / DM);

    float vs = 0.f;
#pragma unroll
    for (int j = 0; j < 4; ++j) {
        float dx = v[j].x - mean, dy = v[j].y - mean, dz = v[j].z - mean, dw = v[j].w - mean;
        vs += dx * dx + dy * dy + dz * dz + dw * dw;
    }
#pragma unroll
    for (int off = 1; off < 64; off <<= 1) vs += __shfl_xor(vs, off);
    float rstd = rsqrtf(vs * (1.f / DM) + 1e-5f);

#pragma unroll
    for (int j = 0; j < 4; ++j) {
        int idx = lane + 64 * j;
        float4 g = ((const float4*)gamma)[idx];
        float4 bt = ((const float4*)beta)[idx];
        float4 o;
        o.x = (v[j].x - mean) * rstd * g.x + bt.x;
        o.y = (v[j].y - mean) * rstd * g.y + bt.y;
        o.z = (v[j].z - mean) * rstd * g.z + bt.z;
        o.w = (v[j].w - mean) * rstd * g.w + bt.w;
        ((float4*)rp)[idx] = o;
    }
}

extern "C" void kernel_launch(void* const* d_in, const int* in_sizes, int n_in,
                              void* d_out, int out_size, void* d_ws, size_t ws_size,
                              hipStream_t stream) {
    const float* Q    = (const float*)d_in[0];
    const float* K    = (const float*)d_in[1];
    const float* V    = (const float*)d_in[2];
    const int*   mask = (const int*)d_in[3];
    const float* Wq   = (const float*)d_in[4];
    const float* bq   = (const float*)d_in[5];
    const float* Wk   = (const float*)d_in[6];
    const float* bk   = (const float*)d_in[7];
    const float* Wv   = (const float*)d_in[8];
    const float* bv   = (const float*)d_in[9];
    const float* Wo   = (const float*)d_in[10];
    const float* bo   = (const float*)d_in[11];
    const float* gamma = (const float*)d_in[12];
    const float* beta  = (const float*)d_in[13];
    float* out = (float*)d_out;

    char* ws = (char*)d_ws;
    const size_t MB = 1024 * 1024;
    f16* wq16 = (f16*)(ws + 0 * MB);
    f16* wk16 = (f16*)(ws + 2 * MB);
    f16* wv16 = (f16*)(ws + 4 * MB);
    f16* wo16 = (f16*)(ws + 6 * MB);
    f16* c16  = (f16*)(ws + 8 * MB);
    f16* q16  = (f16*)(ws + 24 * MB);
    f16* k16  = (f16*)(ws + 40 * MB);
    f16* v16t = (f16*)(ws + 56 * MB);  // total 72 MB

    // packed mask lives in the tail of d_out; oproj overwrites all of out later
    unsigned* pm = (unsigned*)((char*)d_out + (size_t)out_size * 4 - 4096);

    cvt_weights<<<dim3(DM * DM / (256 * 4)), dim3(256), 0, stream>>>(
        Wq, Wk, Wv, Wo, wq16, wk16, wv16, wo16, mask, pm);

    const float qscale = 0.125f * 1.44269504f;   // 1/sqrt(DH) * log2(e)

    gemm_proj3<<<dim3(ROWS / BM, DM / BN, 3), dim3(256), 0, stream>>>(
        Q, K, V, wq16, wk16, wv16, bq, bk, bv, q16, k16, v16t, qscale);

    attn_kernel<<<dim3(SEQ / 128, BB * NH), dim3(256), 0, stream>>>(
        q16, k16, v16t, pm, c16);

    gemm_oproj<<<dim3(ROWS / BM, DM / BN), dim3(256), 0, stream>>>(
        c16, wo16, bo, Q, out);

    ln_kernel<<<dim3(ROWS / 4), dim3(256), 0, stream>>>(out, gamma, beta);
}

// Round 21
// 237.171 us; speedup vs baseline: 1.0539x; 1.0539x over previous
//
#include <hip/hip_runtime.h>

#define SEQ 2048
#define BB 4
#define DM 1024
#define NH 16
#define DH 64
#define ROWS (BB*SEQ)

#define BM 128
#define BN 128
#define BK 32
#define KSTEPS (DM / BK)

#define KVBLK 64
#define NT (SEQ / KVBLK)
#define NBUF 3

typedef _Float16 f16;
typedef _Float16 f16x8 __attribute__((ext_vector_type(8)));
typedef _Float16 f16x4 __attribute__((ext_vector_type(4)));
typedef __fp16 h2 __attribute__((ext_vector_type(2)));
typedef float f32x4 __attribute__((ext_vector_type(4)));
typedef float f32x16 __attribute__((ext_vector_type(16)));
typedef unsigned u32x4 __attribute__((ext_vector_type(4)));

__device__ __forceinline__ f32x4 mfma16(f16x8 a, f16x8 b, f32x4 c) {
    return __builtin_amdgcn_mfma_f32_16x16x32_f16(a, b, c, 0, 0, 0);
}
__device__ __forceinline__ f32x16 mfma32(f16x8 a, f16x8 b, f32x16 c) {
    return __builtin_amdgcn_mfma_f32_32x32x16_f16(a, b, c, 0, 0, 0);
}
__device__ __forceinline__ unsigned pkh(float a, float b) {
    auto h = __builtin_amdgcn_cvt_pkrtz(a, b);   // __fp16 ext_vector(2)
    return __builtin_bit_cast(unsigned, h);
}
// v_dot2_f32_f16: acc += w.x*1 + w.y*1  (sums a packed f16 pair into f32)
__device__ __forceinline__ float sum2(unsigned w, float acc) {
    h2 one = { (__fp16)1.0f, (__fp16)1.0f };
    return __builtin_amdgcn_fdot2(__builtin_bit_cast(h2, w), one, acc, false);
}
// v_permlane32_swap_b32 (vdst=a, vsrc=b):
//   new_a = {lo: a.lo, hi: b.lo};  new_b = {lo: a.hi, hi: b.hi}
__device__ __forceinline__ void plswap(unsigned& a, unsigned& b) {
    auto r = __builtin_amdgcn_permlane32_swap((int)a, (int)b, false, false);
    a = (unsigned)r[0];
    b = (unsigned)r[1];
}
__device__ __forceinline__ float2 plswapf(float x) {
    int xi = __builtin_bit_cast(int, x);
    auto r = __builtin_amdgcn_permlane32_swap(xi, xi, false, false);
    return float2{ __builtin_bit_cast(float, (int)r[0]), __builtin_bit_cast(float, (int)r[1]) };
}
// async global->LDS, 16B per lane; LDS dest = wave-uniform base + lane*16
typedef const __attribute__((address_space(1))) void gvoid;
typedef __attribute__((address_space(3))) void lvoid;
__device__ __forceinline__ void gload16(const f16* g, f16* l) {
    __builtin_amdgcn_global_load_lds((gvoid*)g, (lvoid*)l, 16, 0, 0);
}

// ---------------- weight conversion fp32 -> f16 (+ mask pack in block 0) -------
__global__ __launch_bounds__(256) void cvt_weights(
    const float* __restrict__ wq, const float* __restrict__ wk,
    const float* __restrict__ wv, const float* __restrict__ wo,
    f16* __restrict__ oq, f16* __restrict__ ok,
    f16* __restrict__ ov, f16* __restrict__ oo,
    const int* __restrict__ mask, unsigned* __restrict__ pm) {
    if (blockIdx.x == 0) {
        int tid = threadIdx.x;      // 0..255, packs 32 mask ints each
        const int* mp = mask + (size_t)tid * 32;
        unsigned bits = 0;
#pragma unroll
        for (int j = 0; j < 32; ++j) bits |= (mp[j] != 0 ? 1u : 0u) << j;
        pm[tid] = bits;
    }
    int i = (blockIdx.x * 256 + threadIdx.x) * 4;
    float4 a = *(const float4*)(wq + i);
    float4 b = *(const float4*)(wk + i);
    float4 c = *(const float4*)(wv + i);
    float4 d = *(const float4*)(wo + i);
    f16x4 va = { (f16)a.x, (f16)a.y, (f16)a.z, (f16)a.w };
    f16x4 vb = { (f16)b.x, (f16)b.y, (f16)b.z, (f16)b.w };
    f16x4 vc = { (f16)c.x, (f16)c.y, (f16)c.z, (f16)c.w };
    f16x4 vd = { (f16)d.x, (f16)d.y, (f16)d.z, (f16)d.w };
    *(f16x4*)(oq + i) = va;
    *(f16x4*)(ok + i) = vb;
    *(f16x4*)(ov + i) = vc;
    *(f16x4*)(oo + i) = vd;
}

// ---------------- fused 3-way QKV projection GEMM (A fp32, cvt in-kernel) ------
// grid (ROWS/BM, DM/BN, 3): z selects {Q,K,V} projection.
// mode 0: write [b][h][s][dh]; mode 2: write [b][h][dh][s] via LDS transpose
// (coalesced column stores instead of per-lane SEQ-stride scatter).
__global__ __launch_bounds__(256, 3) void gemm_proj3(
    const float* __restrict__ Qf, const float* __restrict__ Kf,
    const float* __restrict__ Vf,
    const f16* __restrict__ wq, const f16* __restrict__ wk,
    const f16* __restrict__ wv,
    const float* __restrict__ bq, const float* __restrict__ bk,
    const float* __restrict__ bv,
    f16* __restrict__ q16o, f16* __restrict__ k16o, f16* __restrict__ v16o,
    float qscale) {
    const float* A; const f16* W; const float* bias; f16* out;
    float scale; int mode;
    if (blockIdx.z == 0)      { A = Qf; W = wq; bias = bq; out = q16o; scale = qscale; mode = 0; }
    else if (blockIdx.z == 1) { A = Kf; W = wk; bias = bk; out = k16o; scale = 1.0f;   mode = 0; }
    else                      { A = Vf; W = wv; bias = bv; out = v16o; scale = 1.0f;   mode = 2; }

    __shared__ f16 lds_a[2][BM][BK + 8];   // reg-staged, padded (2-way max)
    __shared__ f16 lds_b[2][BN][BK];       // gload16-staged, XOR-swizzled
    const int tid = threadIdx.x;
    const int lane = tid & 63;
    const int wv_ = tid >> 6;
    const int wr = wv_ >> 1, wc = wv_ & 1;
    const int lo = lane & 15, hi = lane >> 4;
    const int rowbase = blockIdx.x * BM;
    const int colbase = blockIdx.y * BN;
    const int ar = tid >> 1;            // A row 0..127
    const int ac = (tid & 1) * 16;      // A col half

    f32x4 acc[4][4];
#pragma unroll
    for (int m = 0; m < 4; ++m)
#pragma unroll
        for (int n = 0; n < 4; ++n) acc[m][n] = (f32x4){0.f, 0.f, 0.f, 0.f};

    float4 av0, av1, av2, av3;
#define LOAD_A(k0)                                                                  \
    {                                                                               \
        const float* ap_ = A + (size_t)(rowbase + ar) * DM + (k0) + ac;             \
        av0 = *(const float4*)(ap_);                                                \
        av1 = *(const float4*)(ap_ + 4);                                            \
        av2 = *(const float4*)(ap_ + 8);                                            \
        av3 = *(const float4*)(ap_ + 12);                                           \
    }
#define WRITE_A(buf)                                                                \
    {                                                                               \
        f16* dp_ = &lds_a[buf][ar][ac];                                             \
        u32x4 t0_ = { pkh(av0.x, av0.y), pkh(av0.z, av0.w),                         \
                      pkh(av1.x, av1.y), pkh(av1.z, av1.w) };                       \
        u32x4 t1_ = { pkh(av2.x, av2.y), pkh(av2.z, av2.w),                         \
                      pkh(av3.x, av3.y), pkh(av3.z, av3.w) };                       \
        *(u32x4*)(dp_) = t0_;                                                       \
        *(u32x4*)(dp_ + 8) = t1_;                                                   \
    }
#define STAGE_W(buf, k0)                                                            \
    {                                                                               \
        int r_ = lane >> 2;                                                         \
        int kc_ = (((lane & 3) ^ ((r_ >> 1) & 3))) * 8;                             \
        gload16(W + (size_t)(colbase + wv_ * 16 + r_) * DM + (k0) + kc_,            \
                &lds_b[buf][wv_ * 16][0]);                                          \
        gload16(W + (size_t)(colbase + (wv_ + 4) * 16 + r_) * DM + (k0) + kc_,      \
                &lds_b[buf][(wv_ + 4) * 16][0]);                                    \
    }

    LOAD_A(0)
    STAGE_W(0, 0)
    WRITE_A(0)
    __syncthreads();
    int buf = 0;
    for (int ks = 0; ks < KSTEPS; ++ks) {
        if (ks + 1 < KSTEPS) {
            LOAD_A((ks + 1) * BK)
            STAGE_W(buf ^ 1, (ks + 1) * BK)
        }
        f16x8 af[4], bf[4];
#pragma unroll
        for (int m = 0; m < 4; ++m)
            af[m] = *(const f16x8*)&lds_a[buf][wr * 64 + m * 16 + lo][hi * 8];
#pragma unroll
        for (int n = 0; n < 4; ++n) {
            int Rn = wc * 64 + n * 16 + lo;
            bf[n] = *(const f16x8*)&lds_b[buf][Rn][(hi ^ ((Rn >> 1) & 3)) * 8];
        }
#pragma unroll
        for (int m = 0; m < 4; ++m)
#pragma unroll
            for (int n = 0; n < 4; ++n)
                acc[m][n] = mfma16(af[m], bf[n], acc[m][n]);
        if (ks + 1 < KSTEPS) WRITE_A(buf ^ 1)     // vm-wait lands after MFMAs
        __syncthreads();
        buf ^= 1;
    }
#undef LOAD_A
#undef WRITE_A
#undef STAGE_W

    if (mode == 2) {
        // ---- V^T epilogue: stage [32 cols][128 rows] per n in LDS, write
        //      coalesced columns (32B/thread contiguous, 256B per 8 threads) ----
        f16* tb = &lds_b[0][0][0];          // 32*136 f16 = 8.7 KB (< 16 KB)
        const int ccolw = wc * 16 + lo;     // this thread's staging column
#pragma unroll
        for (int n = 0; n < 4; ++n) {
            __syncthreads();
            float bv_ = bias[colbase + wc * 64 + n * 16 + lo];
#pragma unroll
            for (int m = 0; m < 4; ++m)
#pragma unroll
                for (int r = 0; r < 4; ++r) {
                    int rowl = wr * 64 + m * 16 + hi * 4 + r;
                    tb[ccolw * 136 + rowl] = (f16)((acc[m][n][r] + bv_) * scale);
                }
            __syncthreads();
            int ccol = tid >> 3;            // 0..31
            int r0 = (tid & 7) * 16;        // 0..112
            int colg = colbase + (ccol >> 4) * 64 + n * 16 + (ccol & 15);
            int hh = colg >> 6, dh = colg & 63;
            int row = rowbase + r0;
            int bi = row >> 11, ss = row & (SEQ - 1);
            f16* dst = out + (((size_t)(bi * NH + hh) * DH + dh) * SEQ + ss);
            f16x8 v0 = *(const f16x8*)&tb[ccol * 136 + r0];
            f16x8 v1 = *(const f16x8*)&tb[ccol * 136 + r0 + 8];
            *(f16x8*)(dst) = v0;
            *(f16x8*)(dst + 8) = v1;
        }
    } else {
#pragma unroll
        for (int n = 0; n < 4; ++n) {
            int col = colbase + wc * 64 + n * 16 + lo;
            float bv_ = bias[col];
            int hh = col >> 6, dh = col & 63;
#pragma unroll
            for (int m = 0; m < 4; ++m)
#pragma unroll
                for (int r = 0; r < 4; ++r) {
                    int row = rowbase + wr * 64 + m * 16 + hi * 4 + r;
                    int bi = row >> 11;
                    int ss = row & (SEQ - 1);
                    float v = (acc[m][n][r] + bv_) * scale;
                    out[(((size_t)(bi * NH + hh) * SEQ + ss) * DH + dh)] = (f16)v;
                }
        }
    }
}

// ---------------- GEMM, output projection + bias + residual (swizzled LDS) -----
__global__ __launch_bounds__(256, 3) void gemm_oproj(
    const f16* __restrict__ A, const f16* __restrict__ W,
    const float* __restrict__ bo, const float* __restrict__ Qin,
    float* __restrict__ out) {
    __shared__ f16 lds_a[2][BM][BK];
    __shared__ f16 lds_b[2][BN][BK];
    const int lane = threadIdx.x & 63;
    const int wv = threadIdx.x >> 6;
    const int wr = wv >> 1, wc = wv & 1;
    const int lo = lane & 15, hi = lane >> 4;
    const int rowbase = blockIdx.x * BM;
    const int colbase = blockIdx.y * BN;

    f32x4 acc[4][4];
#pragma unroll
    for (int m = 0; m < 4; ++m)
#pragma unroll
        for (int n = 0; n < 4; ++n) acc[m][n] = (f32x4){0.f, 0.f, 0.f, 0.f};

#define STAGE_TILES(buf, k0)                                                        \
    {                                                                               \
        int r_ = lane >> 2;                                                         \
        int kc_ = (((lane & 3) ^ ((r_ >> 1) & 3))) * 8;                             \
        gload16(A + (size_t)(rowbase + wv * 16 + r_) * DM + (k0) + kc_,             \
                &lds_a[buf][wv * 16][0]);                                           \
        gload16(A + (size_t)(rowbase + (wv + 4) * 16 + r_) * DM + (k0) + kc_,       \
                &lds_a[buf][(wv + 4) * 16][0]);                                     \
        gload16(W + (size_t)(colbase + wv * 16 + r_) * DM + (k0) + kc_,             \
                &lds_b[buf][wv * 16][0]);                                           \
        gload16(W + (size_t)(colbase + (wv + 4) * 16 + r_) * DM + (k0) + kc_,       \
                &lds_b[buf][(wv + 4) * 16][0]);                                     \
    }

    STAGE_TILES(0, 0)
    __syncthreads();
    int buf = 0;
    for (int ks = 0; ks < KSTEPS; ++ks) {
        if (ks + 1 < KSTEPS) STAGE_TILES(buf ^ 1, (ks + 1) * BK)
        f16x8 af[4], bf[4];
#pragma unroll
        for (int m = 0; m < 4; ++m) {
            int Rm = wr * 64 + m * 16 + lo;
            af[m] = *(const f16x8*)&lds_a[buf][Rm][(hi ^ ((Rm >> 1) & 3)) * 8];
        }
#pragma unroll
        for (int n = 0; n < 4; ++n) {
            int Rn = wc * 64 + n * 16 + lo;
            bf[n] = *(const f16x8*)&lds_b[buf][Rn][(hi ^ ((Rn >> 1) & 3)) * 8];
        }
#pragma unroll
        for (int m = 0; m < 4; ++m)
#pragma unroll
            for (int n = 0; n < 4; ++n)
                acc[m][n] = mfma16(af[m], bf[n], acc[m][n]);
        __syncthreads();
        buf ^= 1;
    }
#undef STAGE_TILES

#pragma unroll
    for (int n = 0; n < 4; ++n) {
        int col = colbase + wc * 64 + n * 16 + lo;
        float bv = bo[col];
#pragma unroll
        for (int m = 0; m < 4; ++m)
#pragma unroll
            for (int r = 0; r < 4; ++r) {
                int row = rowbase + wr * 64 + m * 16 + hi * 4 + r;
                size_t idx = (size_t)row * DM + col;
                out[idx] = acc[m][n][r] + bv + Qin[idx];
            }
    }
}

// ---------------- fused flash attention: 64-key tiles, 1 barrier per tile ------
// grid: (SEQ/128, BB*NH), block 256 (4 waves x 32 q-rows). LDS 48 KB (3 bufs).
// Fixed-shift softmax (C=0), raw v_exp_f32, l via dot2, l-reduce deferred.
__global__ __launch_bounds__(256, 3) void attn_kernel(
    const f16* __restrict__ q16, const f16* __restrict__ k16,
    const f16* __restrict__ v16t, const unsigned* __restrict__ pm,
    f16* __restrict__ out16) {
    __shared__ f16 smem[NBUF][2][KVBLK * 64];    // [buf][K/V][4096 f16] = 48 KB
    const int tid = threadIdx.x;
    const int lane = tid & 63;
    const int wv = tid >> 6;
    const int lo = lane & 31, hw = lane >> 5;
    const int bh = blockIdx.y;
    const int b = bh >> 4, hd = bh & 15;
    const int q0 = blockIdx.x * 128 + wv * 32;

    const f16* qp = q16 + ((size_t)bh * SEQ + q0 + lo) * DH + hw * 8;
    const f16* kp = k16 + (size_t)bh * SEQ * DH;
    const f16* vp = v16t + (size_t)bh * DH * SEQ;
    const unsigned* pmb = pm + b * 64;

    // staging: 8 lanes/row; rows [wv*8, wv*8+8) and [32+wv*8, 32+wv*8+8)
    const int sr = lane >> 3, scb = lane & 7;
    const int cb = scb ^ sr;               // col-block loaded into slot scb

    f16x8 qb[4];
#pragma unroll
    for (int c = 0; c < 4; ++c) qb[c] = *(const f16x8*)(qp + c * 16);

    f32x16 fz;
#pragma unroll
    for (int i = 0; i < 16; ++i) fz[i] = 0.f;
    f32x16 ctx0 = fz, ctx1 = fz;
    float la = 0.f, lb = 0.f;    // own-half partial l (dot2-accumulated)

    // 4 gload16 per wave per STAGE; K tile [64 keys][64 dh], V^T tile [64 dh][64 k]
#define STAGE(buf, KB)                                                              \
    {                                                                               \
        gload16(kp + (size_t)((KB) + wv * 8 + sr) * DH + cb * 8,                    \
                &smem[buf][0][wv * 512]);                                           \
        gload16(kp + (size_t)((KB) + 32 + wv * 8 + sr) * DH + cb * 8,               \
                &smem[buf][0][(4 + wv) * 512]);                                     \
        gload16(vp + (size_t)(wv * 8 + sr) * SEQ + (KB) + cb * 8,                   \
                &smem[buf][1][wv * 512]);                                           \
        gload16(vp + (size_t)(32 + wv * 8 + sr) * SEQ + (KB) + cb * 8,              \
                &smem[buf][1][(4 + wv) * 512]);                                     \
    }

    STAGE(0, 0)
    STAGE(1, KVBLK)

    int bc = 0;                       // t % NBUF
    for (int t = 0; t < NT; ++t) {
        // counted wait: own STAGE(t) (4 loads) landed; STAGE(t+1) may stay in flight
        if (t < NT - 1) asm volatile("s_waitcnt vmcnt(4)" ::: "memory");
        else            asm volatile("s_waitcnt vmcnt(0)" ::: "memory");
        __builtin_amdgcn_s_barrier();
        asm volatile("" ::: "memory");

        const f16* kbase = &smem[bc][0][0];
        const f16* vbase = &smem[bc][1][0];

        // ---- prefetch 2 tiles ahead (into buffer last read at tile t-1) ----
        if (t + 2 < NT) {
            int bs = bc + 2; if (bs >= NBUF) bs -= NBUF;
            STAGE(bs, (t + 2) * KVBLK)
        }

        unsigned bmw0 = pmb[2 * t];
        unsigned bmw1 = pmb[2 * t + 1];

#pragma unroll
        for (int kt = 0; kt < 2; ++kt) {
            // ---- K fragments: row kt*32+lo, d-slot (2c+hw)^(lo&7) ----
            f16x8 kf0 = *(const f16x8*)&kbase[(kt * 32 + lo) * 64 + (((0 + hw) ^ (lo & 7)) << 3)];
            f16x8 kf1 = *(const f16x8*)&kbase[(kt * 32 + lo) * 64 + (((2 + hw) ^ (lo & 7)) << 3)];

            f32x16 st;
            __builtin_amdgcn_s_setprio(1);
            st = mfma32(kf0, qb[0], fz);
            f16x8 kf2 = *(const f16x8*)&kbase[(kt * 32 + lo) * 64 + (((4 + hw) ^ (lo & 7)) << 3)];
            st = mfma32(kf1, qb[1], st);
            f16x8 kf3 = *(const f16x8*)&kbase[(kt * 32 + lo) * 64 + (((6 + hw) ^ (lo & 7)) << 3)];
            st = mfma32(kf2, qb[2], st);
            st = mfma32(kf3, qb[3], st);
            __builtin_amdgcn_s_setprio(0);

            // ---- mask (packed bits) ----
            unsigned bm = kt ? bmw1 : bmw0;
            if (bm != 0xffffffffu) {
                unsigned bs_ = bm >> (hw * 4);
#pragma unroll
                for (int r = 0; r < 16; ++r)
                    if (!((bs_ >> ((r & 3) + 8 * (r >> 2))) & 1)) st[r] = -1e9f;
            }

            // ---- P = exp2(s) (raw v_exp_f32) ----
#pragma unroll
            for (int i = 0; i < 16; ++i) st[i] = __builtin_amdgcn_exp2f(st[i]);

            // ---- pack, l via dot2, vf reads, PV MFMAs ----
            __builtin_amdgcn_s_setprio(1);
            {
                unsigned w0 = pkh(st[0], st[1]),   w1 = pkh(st[2], st[3]);
                unsigned w2 = pkh(st[4], st[5]),   w3 = pkh(st[6], st[7]);
                unsigned w4 = pkh(st[8], st[9]),   w5 = pkh(st[10], st[11]);
                unsigned w6 = pkh(st[12], st[13]), w7 = pkh(st[14], st[15]);
                la = sum2(w0, la); lb = sum2(w1, lb);
                la = sum2(w2, la); lb = sum2(w3, lb);
                la = sum2(w4, la); lb = sum2(w5, lb);
                la = sum2(w6, la); lb = sum2(w7, lb);
                f16x8 vf00 = *(const f16x8*)&vbase[(0 * 32 + lo) * 64 + (((kt * 4 + 0 + hw) ^ (lo & 7)) << 3)];
                f16x8 vf10 = *(const f16x8*)&vbase[(1 * 32 + lo) * 64 + (((kt * 4 + 0 + hw) ^ (lo & 7)) << 3)];
                {
                    unsigned a0 = w0, b0 = w2; plswap(a0, b0);
                    unsigned a1 = w1, b1 = w3; plswap(a1, b1);
                    u32x4 t_ = { a0, a1, b0, b1 };
                    f16x8 pb = __builtin_bit_cast(f16x8, t_);
                    ctx0 = mfma32(vf00, pb, ctx0);
                    ctx1 = mfma32(vf10, pb, ctx1);
                }
                f16x8 vf01 = *(const f16x8*)&vbase[(0 * 32 + lo) * 64 + (((kt * 4 + 2 + hw) ^ (lo & 7)) << 3)];
                f16x8 vf11 = *(const f16x8*)&vbase[(1 * 32 + lo) * 64 + (((kt * 4 + 2 + hw) ^ (lo & 7)) << 3)];
                {
                    unsigned a0 = w4, b0 = w6; plswap(a0, b0);
                    unsigned a1 = w5, b1 = w7; plswap(a1, b1);
                    u32x4 t_ = { a0, a1, b0, b1 };
                    f16x8 pb = __builtin_bit_cast(f16x8, t_);
                    ctx0 = mfma32(vf01, pb, ctx0);
                    ctx1 = mfma32(vf11, pb, ctx1);
                }
            }
            __builtin_amdgcn_s_setprio(0);
        }

        bc = (bc + 1 == NBUF) ? 0 : bc + 1;
    }
#undef STAGE

    __syncthreads();   // all waves done with smem tiles before transpose reuse

    // ---- epilogue: combine l halves (deferred), divide, transpose, store ----
    float lown = la + lb;
    float2 lp = plswapf(lown);
    float rl = 1.0f / (lp.x + lp.y);
    f16* tbp = &smem[0][0][0] + wv * (32 * 66);
#pragma unroll
    for (int u = 0; u < 8; ++u) {
        int d0 = 2 * (u & 1) + 8 * (u >> 1) + 4 * hw;
        unsigned pw0 = pkh(ctx0[2 * u] * rl, ctx0[2 * u + 1] * rl);
        unsigned pw1 = pkh(ctx1[2 * u] * rl, ctx1[2 * u + 1] * rl);
        *(unsigned*)&tbp[lo * 66 + d0] = pw0;
        *(unsigned*)&tbp[lo * 66 + 32 + d0] = pw1;
    }
    __syncthreads();
#pragma unroll
    for (int it = 0; it < 4; ++it) {
        int r = it * 8 + (lane >> 3);
        const unsigned* src = (const unsigned*)(tbp + r * 66);
        int cc = (lane & 7) * 4;
        u32x4 t = { src[cc], src[cc + 1], src[cc + 2], src[cc + 3] };
        f16x8 vvv = __builtin_bit_cast(f16x8, t);
        *(f16x8*)(out16 + ((size_t)(b * SEQ) + q0 + r) * DM + hd * 64 + (lane & 7) * 8) = vvv;
    }
}

// ---------------- in-place LayerNorm ----------------
__global__ __launch_bounds__(256) void ln_kernel(
    float* __restrict__ x, const float* __restrict__ gamma,
    const float* __restrict__ beta) {
    const int lane = threadIdx.x & 63;
    const int wave = threadIdx.x >> 6;
    const int row = blockIdx.x * 4 + wave;
    float* rp = x + (size_t)row * DM;

    float4 v[4];
#pragma unroll
    for (int j = 0; j < 4; ++j) v[j] = ((const float4*)rp)[lane + 64 * j];

    float sum = 0.f;
#pragma unroll
    for (int j = 0; j < 4; ++j) sum += v[j].x + v[j].y + v[j].z + v[j].w;
#pragma unroll
    for (int off = 1; off < 64; off <<= 1) sum += __shfl_xor(sum, off);
    float mean = sum * (1.f / DM);

    float vs = 0.f;
#pragma unroll
    for (int j = 0; j < 4; ++j) {
        float dx = v[j].x - mean, dy = v[j].y - mean, dz = v[j].z - mean, dw = v[j].w - mean;
        vs += dx * dx + dy * dy + dz * dz + dw * dw;
    }
#pragma unroll
    for (int off = 1; off < 64; off <<= 1) vs += __shfl_xor(vs, off);
    float rstd = rsqrtf(vs * (1.f / DM) + 1e-5f);

#pragma unroll
    for (int j = 0; j < 4; ++j) {
        int idx = lane + 64 * j;
        float4 g = ((const float4*)gamma)[idx];
        float4 bt = ((const float4*)beta)[idx];
        float4 o;
        o.x = (v[j].x - mean) * rstd * g.x + bt.x;
        o.y = (v[j].y - mean) * rstd * g.y + bt.y;
        o.z = (v[j].z - mean) * rstd * g.z + bt.z;
        o.w = (v[j].w - mean) * rstd * g.w + bt.w;
        ((float4*)rp)[idx] = o;
    }
}

extern "C" void kernel_launch(void* const* d_in, const int* in_sizes, int n_in,
                              void* d_out, int out_size, void* d_ws, size_t ws_size,
                              hipStream_t stream) {
    const float* Q    = (const float*)d_in[0];
    const float* K    = (const float*)d_in[1];
    const float* V    = (const float*)d_in[2];
    const int*   mask = (const int*)d_in[3];
    const float* Wq   = (const float*)d_in[4];
    const float* bq   = (const float*)d_in[5];
    const float* Wk   = (const float*)d_in[6];
    const float* bk   = (const float*)d_in[7];
    const float* Wv   = (const float*)d_in[8];
    const float* bv   = (const float*)d_in[9];
    const float* Wo   = (const float*)d_in[10];
    const float* bo   = (const float*)d_in[11];
    const float* gamma = (const float*)d_in[12];
    const float* beta  = (const float*)d_in[13];
    float* out = (float*)d_out;

    char* ws = (char*)d_ws;
    const size_t MB = 1024 * 1024;
    f16* wq16 = (f16*)(ws + 0 * MB);
    f16* wk16 = (f16*)(ws + 2 * MB);
    f16* wv16 = (f16*)(ws + 4 * MB);
    f16* wo16 = (f16*)(ws + 6 * MB);
    f16* c16  = (f16*)(ws + 8 * MB);
    f16* q16  = (f16*)(ws + 24 * MB);
    f16* k16  = (f16*)(ws + 40 * MB);
    f16* v16t = (f16*)(ws + 56 * MB);  // total 72 MB

    // packed mask lives in the tail of d_out; oproj overwrites all of out later
    unsigned* pm = (unsigned*)((char*)d_out + (size_t)out_size * 4 - 4096);

    cvt_weights<<<dim3(DM * DM / (256 * 4)), dim3(256), 0, stream>>>(
        Wq, Wk, Wv, Wo, wq16, wk16, wv16, wo16, mask, pm);

    const float qscale = 0.125f * 1.44269504f;   // 1/sqrt(DH) * log2(e)

    gemm_proj3<<<dim3(ROWS / BM, DM / BN, 3), dim3(256), 0, stream>>>(
        Q, K, V, wq16, wk16, wv16, bq, bk, bv, q16, k16, v16t, qscale);

    attn_kernel<<<dim3(SEQ / 128, BB * NH), dim3(256), 0, stream>>>(
        q16, k16, v16t, pm, c16);

    gemm_oproj<<<dim3(ROWS / BM, DM / BN), dim3(256), 0, stream>>>(
        c16, wo16, bo, Q, out);

    ln_kernel<<<dim3(ROWS / 4), dim3(256), 0, stream>>>(out, gamma, beta);
}

// Round 22
// 231.970 us; speedup vs baseline: 1.0775x; 1.0224x over previous
//
#include <hip/hip_runtime.h>

#define SEQ 2048
#define BB 4
#define DM 1024
#define NH 16
#define DH 64
#define ROWS (BB*SEQ)

#define BM 128
#define BN 128
#define BK 32
#define KSTEPS (DM / BK)

#define KVBLK 64
#define NT (SEQ / KVBLK)
#define NBUF 3

typedef _Float16 f16;
typedef _Float16 f16x8 __attribute__((ext_vector_type(8)));
typedef _Float16 f16x4 __attribute__((ext_vector_type(4)));
typedef __fp16 h2 __attribute__((ext_vector_type(2)));
typedef float f32x4 __attribute__((ext_vector_type(4)));
typedef float f32x16 __attribute__((ext_vector_type(16)));
typedef unsigned u32x4 __attribute__((ext_vector_type(4)));

__device__ __forceinline__ f32x4 mfma16(f16x8 a, f16x8 b, f32x4 c) {
    return __builtin_amdgcn_mfma_f32_16x16x32_f16(a, b, c, 0, 0, 0);
}
__device__ __forceinline__ f32x16 mfma32(f16x8 a, f16x8 b, f32x16 c) {
    return __builtin_amdgcn_mfma_f32_32x32x16_f16(a, b, c, 0, 0, 0);
}
__device__ __forceinline__ unsigned pkh(float a, float b) {
    auto h = __builtin_amdgcn_cvt_pkrtz(a, b);   // __fp16 ext_vector(2)
    return __builtin_bit_cast(unsigned, h);
}
// v_dot2_f32_f16: acc += w.x*1 + w.y*1  (sums a packed f16 pair into f32)
__device__ __forceinline__ float sum2(unsigned w, float acc) {
    h2 one = { (__fp16)1.0f, (__fp16)1.0f };
    return __builtin_amdgcn_fdot2(__builtin_bit_cast(h2, w), one, acc, false);
}
// v_permlane32_swap_b32 (vdst=a, vsrc=b):
//   new_a = {lo: a.lo, hi: b.lo};  new_b = {lo: a.hi, hi: b.hi}
__device__ __forceinline__ void plswap(unsigned& a, unsigned& b) {
    auto r = __builtin_amdgcn_permlane32_swap((int)a, (int)b, false, false);
    a = (unsigned)r[0];
    b = (unsigned)r[1];
}
__device__ __forceinline__ float2 plswapf(float x) {
    int xi = __builtin_bit_cast(int, x);
    auto r = __builtin_amdgcn_permlane32_swap(xi, xi, false, false);
    return float2{ __builtin_bit_cast(float, (int)r[0]), __builtin_bit_cast(float, (int)r[1]) };
}
// async global->LDS, 16B per lane; LDS dest = wave-uniform base + lane*16
typedef const __attribute__((address_space(1))) void gvoid;
typedef __attribute__((address_space(3))) void lvoid;
__device__ __forceinline__ void gload16(const f16* g, f16* l) {
    __builtin_amdgcn_global_load_lds((gvoid*)g, (lvoid*)l, 16, 0, 0);
}

// ---------------- weight conversion fp32 -> f16 (+ mask pack in block 0) -------
__global__ __launch_bounds__(256) void cvt_weights(
    const float* __restrict__ wq, const float* __restrict__ wk,
    const float* __restrict__ wv, const float* __restrict__ wo,
    f16* __restrict__ oq, f16* __restrict__ ok,
    f16* __restrict__ ov, f16* __restrict__ oo,
    const int* __restrict__ mask, unsigned* __restrict__ pm) {
    if (blockIdx.x == 0) {
        int tid = threadIdx.x;      // 0..255, packs 32 mask ints each
        const int* mp = mask + (size_t)tid * 32;
        unsigned bits = 0;
#pragma unroll
        for (int j = 0; j < 32; ++j) bits |= (mp[j] != 0 ? 1u : 0u) << j;
        pm[tid] = bits;
    }
    int i = (blockIdx.x * 256 + threadIdx.x) * 4;
    float4 a = *(const float4*)(wq + i);
    float4 b = *(const float4*)(wk + i);
    float4 c = *(const float4*)(wv + i);
    float4 d = *(const float4*)(wo + i);
    f16x4 va = { (f16)a.x, (f16)a.y, (f16)a.z, (f16)a.w };
    f16x4 vb = { (f16)b.x, (f16)b.y, (f16)b.z, (f16)b.w };
    f16x4 vc = { (f16)c.x, (f16)c.y, (f16)c.z, (f16)c.w };
    f16x4 vd = { (f16)d.x, (f16)d.y, (f16)d.z, (f16)d.w };
    *(f16x4*)(oq + i) = va;
    *(f16x4*)(ok + i) = vb;
    *(f16x4*)(ov + i) = vc;
    *(f16x4*)(oo + i) = vd;
}

// ---------------- fused 3-way QKV projection GEMM (A fp32, cvt in-kernel) ------
// grid (ROWS/BM, DM/BN, 3): z selects {Q,K,V} projection.
// K-loop uses raw s_barrier + counted vmcnt: A prefetched 2 K-steps ahead in
// registers (depth-2, ~2 iters of HBM-latency cover); W gload16 gets 1 iter.
// Issue order per iter: STAGE_W(ks+1)[2vm] -> LOAD_A(ks+2)[4vm] -> MFMAs ->
// WRITE_A(cur) -> vmcnt(4)+lgkmcnt(0)+s_barrier (A loads stay in flight).
__global__ __launch_bounds__(256, 3) void gemm_proj3(
    const float* __restrict__ Qf, const float* __restrict__ Kf,
    const float* __restrict__ Vf,
    const f16* __restrict__ wq, const f16* __restrict__ wk,
    const f16* __restrict__ wv,
    const float* __restrict__ bq, const float* __restrict__ bk,
    const float* __restrict__ bv,
    f16* __restrict__ q16o, f16* __restrict__ k16o, f16* __restrict__ v16o,
    float qscale) {
    const float* A; const f16* W; const float* bias; f16* out;
    float scale; int mode;
    if (blockIdx.z == 0)      { A = Qf; W = wq; bias = bq; out = q16o; scale = qscale; mode = 0; }
    else if (blockIdx.z == 1) { A = Kf; W = wk; bias = bk; out = k16o; scale = 1.0f;   mode = 0; }
    else                      { A = Vf; W = wv; bias = bv; out = v16o; scale = 1.0f;   mode = 2; }

    __shared__ f16 lds_a[2][BM][BK + 8];   // reg-staged, padded (2-way max)
    __shared__ f16 lds_b[2][BN][BK];       // gload16-staged, XOR-swizzled
    const int tid = threadIdx.x;
    const int lane = tid & 63;
    const int wv_ = tid >> 6;
    const int wr = wv_ >> 1, wc = wv_ & 1;
    const int lo = lane & 15, hi = lane >> 4;
    const int rowbase = blockIdx.x * BM;
    const int colbase = blockIdx.y * BN;
    const int ar = tid >> 1;            // A row 0..127
    const int ac = (tid & 1) * 16;      // A col half

    f32x4 acc[4][4];
#pragma unroll
    for (int m = 0; m < 4; ++m)
#pragma unroll
        for (int n = 0; n < 4; ++n) acc[m][n] = (f32x4){0.f, 0.f, 0.f, 0.f};

    float4 avP0, avP1, avP2, avP3;      // two register A-tiles (depth-2)
    float4 avQ0, avQ1, avQ2, avQ3;
#define LOAD_A(V0, V1, V2, V3, k0)                                                  \
    {                                                                               \
        const float* ap_ = A + (size_t)(rowbase + ar) * DM + (k0) + ac;             \
        V0 = *(const float4*)(ap_);                                                 \
        V1 = *(const float4*)(ap_ + 4);                                             \
        V2 = *(const float4*)(ap_ + 8);                                             \
        V3 = *(const float4*)(ap_ + 12);                                            \
    }
#define WRITE_A(buf, V0, V1, V2, V3)                                                \
    {                                                                               \
        f16* dp_ = &lds_a[buf][ar][ac];                                             \
        u32x4 t0_ = { pkh(V0.x, V0.y), pkh(V0.z, V0.w),                             \
                      pkh(V1.x, V1.y), pkh(V1.z, V1.w) };                           \
        u32x4 t1_ = { pkh(V2.x, V2.y), pkh(V2.z, V2.w),                             \
                      pkh(V3.x, V3.y), pkh(V3.z, V3.w) };                           \
        *(u32x4*)(dp_) = t0_;                                                       \
        *(u32x4*)(dp_ + 8) = t1_;                                                   \
    }
#define STAGE_W(buf, k0)                                                            \
    {                                                                               \
        int r_ = lane >> 2;                                                         \
        int kc_ = (((lane & 3) ^ ((r_ >> 1) & 3))) * 8;                             \
        gload16(W + (size_t)(colbase + wv_ * 16 + r_) * DM + (k0) + kc_,            \
                &lds_b[buf][wv_ * 16][0]);                                          \
        gload16(W + (size_t)(colbase + (wv_ + 4) * 16 + r_) * DM + (k0) + kc_,      \
                &lds_b[buf][(wv_ + 4) * 16][0]);                                    \
    }

    // prologue: buf0 <- A(0), W(0); avP <- A(BK) left in flight across barrier
    LOAD_A(avP0, avP1, avP2, avP3, 0)
    WRITE_A(0, avP0, avP1, avP2, avP3)          // compiler waits avP loads
    STAGE_W(0, 0)                               // 2 vm (oldest outstanding)
    LOAD_A(avP0, avP1, avP2, avP3, BK)          // 4 vm (newest)
    asm volatile("s_waitcnt vmcnt(4) lgkmcnt(0)" ::: "memory");  // W(0)+ds_write done
    __builtin_amdgcn_s_barrier();
    asm volatile("" ::: "memory");

    int buf = 0;
    // GITER: AVC = data for (ks+1) [written this iter]; AVN receives (ks+2)
#define GITER(ks, AC0, AC1, AC2, AC3, AN0, AN1, AN2, AN3)                           \
    {                                                                               \
        if ((ks) + 1 < KSTEPS) STAGE_W(buf ^ 1, ((ks) + 1) * BK)                    \
        if ((ks) + 2 < KSTEPS) LOAD_A(AN0, AN1, AN2, AN3, ((ks) + 2) * BK)          \
        f16x8 af[4], bf[4];                                                         \
        _Pragma("unroll")                                                           \
        for (int m = 0; m < 4; ++m)                                                 \
            af[m] = *(const f16x8*)&lds_a[buf][wr * 64 + m * 16 + lo][hi * 8];      \
        _Pragma("unroll")                                                           \
        for (int n = 0; n < 4; ++n) {                                               \
            int Rn = wc * 64 + n * 16 + lo;                                         \
            bf[n] = *(const f16x8*)&lds_b[buf][Rn][(hi ^ ((Rn >> 1) & 3)) * 8];     \
        }                                                                           \
        _Pragma("unroll")                                                           \
        for (int m = 0; m < 4; ++m)                                                 \
            _Pragma("unroll")                                                       \
            for (int n = 0; n < 4; ++n)                                             \
                acc[m][n] = mfma16(af[m], bf[n], acc[m][n]);                        \
        if ((ks) + 1 < KSTEPS) {                                                    \
            WRITE_A(buf ^ 1, AC0, AC1, AC2, AC3)                                    \
            if ((ks) + 2 < KSTEPS)                                                  \
                asm volatile("s_waitcnt vmcnt(4) lgkmcnt(0)" ::: "memory");         \
            else                                                                    \
                asm volatile("s_waitcnt vmcnt(0) lgkmcnt(0)" ::: "memory");         \
            __builtin_amdgcn_s_barrier();                                           \
            asm volatile("" ::: "memory");                                          \
        }                                                                           \
        buf ^= 1;                                                                   \
    }

    for (int ks = 0; ks < KSTEPS; ks += 2) {
        GITER(ks,     avP0, avP1, avP2, avP3, avQ0, avQ1, avQ2, avQ3)
        GITER(ks + 1, avQ0, avQ1, avQ2, avQ3, avP0, avP1, avP2, avP3)
    }
#undef LOAD_A
#undef WRITE_A
#undef STAGE_W
#undef GITER

    if (mode == 2) {
        // ---- V^T epilogue: stage [32 cols][128 rows] per n in LDS, write
        //      coalesced columns (32B/thread contiguous) ----
        f16* tb = &lds_b[0][0][0];          // 32*136 f16 = 8.7 KB
        const int ccolw = wc * 16 + lo;     // this thread's staging column
#pragma unroll
        for (int n = 0; n < 4; ++n) {
            __syncthreads();
            float bv_ = bias[colbase + wc * 64 + n * 16 + lo];
#pragma unroll
            for (int m = 0; m < 4; ++m)
#pragma unroll
                for (int r = 0; r < 4; ++r) {
                    int rowl = wr * 64 + m * 16 + hi * 4 + r;
                    tb[ccolw * 136 + rowl] = (f16)((acc[m][n][r] + bv_) * scale);
                }
            __syncthreads();
            int ccol = tid >> 3;            // 0..31
            int r0 = (tid & 7) * 16;        // 0..112
            int colg = colbase + (ccol >> 4) * 64 + n * 16 + (ccol & 15);
            int hh = colg >> 6, dh = colg & 63;
            int row = rowbase + r0;
            int bi = row >> 11, ss = row & (SEQ - 1);
            f16* dst = out + (((size_t)(bi * NH + hh) * DH + dh) * SEQ + ss);
            f16x8 v0 = *(const f16x8*)&tb[ccol * 136 + r0];
            f16x8 v1 = *(const f16x8*)&tb[ccol * 136 + r0 + 8];
            *(f16x8*)(dst) = v0;
            *(f16x8*)(dst + 8) = v1;
        }
    } else {
#pragma unroll
        for (int n = 0; n < 4; ++n) {
            int col = colbase + wc * 64 + n * 16 + lo;
            float bv_ = bias[col];
            int hh = col >> 6, dh = col & 63;
#pragma unroll
            for (int m = 0; m < 4; ++m)
#pragma unroll
                for (int r = 0; r < 4; ++r) {
                    int row = rowbase + wr * 64 + m * 16 + hi * 4 + r;
                    int bi = row >> 11;
                    int ss = row & (SEQ - 1);
                    float v = (acc[m][n][r] + bv_) * scale;
                    out[(((size_t)(bi * NH + hh) * SEQ + ss) * DH + dh)] = (f16)v;
                }
        }
    }
}

// ---------------- GEMM, output projection + bias + residual (swizzled LDS) -----
__global__ __launch_bounds__(256, 3) void gemm_oproj(
    const f16* __restrict__ A, const f16* __restrict__ W,
    const float* __restrict__ bo, const float* __restrict__ Qin,
    float* __restrict__ out) {
    __shared__ f16 lds_a[2][BM][BK];
    __shared__ f16 lds_b[2][BN][BK];
    const int lane = threadIdx.x & 63;
    const int wv = threadIdx.x >> 6;
    const int wr = wv >> 1, wc = wv & 1;
    const int lo = lane & 15, hi = lane >> 4;
    const int rowbase = blockIdx.x * BM;
    const int colbase = blockIdx.y * BN;

    f32x4 acc[4][4];
#pragma unroll
    for (int m = 0; m < 4; ++m)
#pragma unroll
        for (int n = 0; n < 4; ++n) acc[m][n] = (f32x4){0.f, 0.f, 0.f, 0.f};

#define STAGE_TILES(buf, k0)                                                        \
    {                                                                               \
        int r_ = lane >> 2;                                                         \
        int kc_ = (((lane & 3) ^ ((r_ >> 1) & 3))) * 8;                             \
        gload16(A + (size_t)(rowbase + wv * 16 + r_) * DM + (k0) + kc_,             \
                &lds_a[buf][wv * 16][0]);                                           \
        gload16(A + (size_t)(rowbase + (wv + 4) * 16 + r_) * DM + (k0) + kc_,       \
                &lds_a[buf][(wv + 4) * 16][0]);                                     \
        gload16(W + (size_t)(colbase + wv * 16 + r_) * DM + (k0) + kc_,             \
                &lds_b[buf][wv * 16][0]);                                           \
        gload16(W + (size_t)(colbase + (wv + 4) * 16 + r_) * DM + (k0) + kc_,       \
                &lds_b[buf][(wv + 4) * 16][0]);                                     \
    }

    STAGE_TILES(0, 0)
    __syncthreads();
    int buf = 0;
    for (int ks = 0; ks < KSTEPS; ++ks) {
        if (ks + 1 < KSTEPS) STAGE_TILES(buf ^ 1, (ks + 1) * BK)
        f16x8 af[4], bf[4];
#pragma unroll
        for (int m = 0; m < 4; ++m) {
            int Rm = wr * 64 + m * 16 + lo;
            af[m] = *(const f16x8*)&lds_a[buf][Rm][(hi ^ ((Rm >> 1) & 3)) * 8];
        }
#pragma unroll
        for (int n = 0; n < 4; ++n) {
            int Rn = wc * 64 + n * 16 + lo;
            bf[n] = *(const f16x8*)&lds_b[buf][Rn][(hi ^ ((Rn >> 1) & 3)) * 8];
        }
#pragma unroll
        for (int m = 0; m < 4; ++m)
#pragma unroll
            for (int n = 0; n < 4; ++n)
                acc[m][n] = mfma16(af[m], bf[n], acc[m][n]);
        __syncthreads();
        buf ^= 1;
    }
#undef STAGE_TILES

#pragma unroll
    for (int n = 0; n < 4; ++n) {
        int col = colbase + wc * 64 + n * 16 + lo;
        float bv = bo[col];
#pragma unroll
        for (int m = 0; m < 4; ++m)
#pragma unroll
            for (int r = 0; r < 4; ++r) {
                int row = rowbase + wr * 64 + m * 16 + hi * 4 + r;
                size_t idx = (size_t)row * DM + col;
                out[idx] = acc[m][n][r] + bv + Qin[idx];
            }
    }
}

// ---------------- fused flash attention: 64-key tiles, 1 barrier per tile ------
// grid: (SEQ/128, BB*NH), block 256 (4 waves x 32 q-rows). LDS 48 KB (3 bufs).
// Fixed-shift softmax (C=0), raw v_exp_f32, l via dot2, l-reduce deferred.
__global__ __launch_bounds__(256, 3) void attn_kernel(
    const f16* __restrict__ q16, const f16* __restrict__ k16,
    const f16* __restrict__ v16t, const unsigned* __restrict__ pm,
    f16* __restrict__ out16) {
    __shared__ f16 smem[NBUF][2][KVBLK * 64];    // [buf][K/V][4096 f16] = 48 KB
    const int tid = threadIdx.x;
    const int lane = tid & 63;
    const int wv = tid >> 6;
    const int lo = lane & 31, hw = lane >> 5;
    const int bh = blockIdx.y;
    const int b = bh >> 4, hd = bh & 15;
    const int q0 = blockIdx.x * 128 + wv * 32;

    const f16* qp = q16 + ((size_t)bh * SEQ + q0 + lo) * DH + hw * 8;
    const f16* kp = k16 + (size_t)bh * SEQ * DH;
    const f16* vp = v16t + (size_t)bh * DH * SEQ;
    const unsigned* pmb = pm + b * 64;

    // staging: 8 lanes/row; rows [wv*8, wv*8+8) and [32+wv*8, 32+wv*8+8)
    const int sr = lane >> 3, scb = lane & 7;
    const int cb = scb ^ sr;               // col-block loaded into slot scb

    f16x8 qb[4];
#pragma unroll
    for (int c = 0; c < 4; ++c) qb[c] = *(const f16x8*)(qp + c * 16);

    f32x16 fz;
#pragma unroll
    for (int i = 0; i < 16; ++i) fz[i] = 0.f;
    f32x16 ctx0 = fz, ctx1 = fz;
    float la = 0.f, lb = 0.f;    // own-half partial l (dot2-accumulated)

    // 4 gload16 per wave per STAGE; K tile [64 keys][64 dh], V^T tile [64 dh][64 k]
#define STAGE(buf, KB)                                                              \
    {                                                                               \
        gload16(kp + (size_t)((KB) + wv * 8 + sr) * DH + cb * 8,                    \
                &smem[buf][0][wv * 512]);                                           \
        gload16(kp + (size_t)((KB) + 32 + wv * 8 + sr) * DH + cb * 8,               \
                &smem[buf][0][(4 + wv) * 512]);                                     \
        gload16(vp + (size_t)(wv * 8 + sr) * SEQ + (KB) + cb * 8,                   \
                &smem[buf][1][wv * 512]);                                           \
        gload16(vp + (size_t)(32 + wv * 8 + sr) * SEQ + (KB) + cb * 8,              \
                &smem[buf][1][(4 + wv) * 512]);                                     \
    }

    STAGE(0, 0)
    STAGE(1, KVBLK)

    int bc = 0;                       // t % NBUF
    for (int t = 0; t < NT; ++t) {
        // counted wait: own STAGE(t) (4 loads) landed; STAGE(t+1) may stay in flight
        if (t < NT - 1) asm volatile("s_waitcnt vmcnt(4)" ::: "memory");
        else            asm volatile("s_waitcnt vmcnt(0)" ::: "memory");
        __builtin_amdgcn_s_barrier();
        asm volatile("" ::: "memory");

        const f16* kbase = &smem[bc][0][0];
        const f16* vbase = &smem[bc][1][0];

        // ---- prefetch 2 tiles ahead (into buffer last read at tile t-1) ----
        if (t + 2 < NT) {
            int bs = bc + 2; if (bs >= NBUF) bs -= NBUF;
            STAGE(bs, (t + 2) * KVBLK)
        }

        unsigned bmw0 = pmb[2 * t];
        unsigned bmw1 = pmb[2 * t + 1];

#pragma unroll
        for (int kt = 0; kt < 2; ++kt) {
            // ---- K fragments: row kt*32+lo, d-slot (2c+hw)^(lo&7) ----
            f16x8 kf0 = *(const f16x8*)&kbase[(kt * 32 + lo) * 64 + (((0 + hw) ^ (lo & 7)) << 3)];
            f16x8 kf1 = *(const f16x8*)&kbase[(kt * 32 + lo) * 64 + (((2 + hw) ^ (lo & 7)) << 3)];

            f32x16 st;
            __builtin_amdgcn_s_setprio(1);
            st = mfma32(kf0, qb[0], fz);
            f16x8 kf2 = *(const f16x8*)&kbase[(kt * 32 + lo) * 64 + (((4 + hw) ^ (lo & 7)) << 3)];
            st = mfma32(kf1, qb[1], st);
            f16x8 kf3 = *(const f16x8*)&kbase[(kt * 32 + lo) * 64 + (((6 + hw) ^ (lo & 7)) << 3)];
            st = mfma32(kf2, qb[2], st);
            st = mfma32(kf3, qb[3], st);
            __builtin_amdgcn_s_setprio(0);

            // ---- mask (packed bits) ----
            unsigned bm = kt ? bmw1 : bmw0;
            if (bm != 0xffffffffu) {
                unsigned bs_ = bm >> (hw * 4);
#pragma unroll
                for (int r = 0; r < 16; ++r)
                    if (!((bs_ >> ((r & 3) + 8 * (r >> 2))) & 1)) st[r] = -1e9f;
            }

            // ---- P = exp2(s) (raw v_exp_f32) ----
#pragma unroll
            for (int i = 0; i < 16; ++i) st[i] = __builtin_amdgcn_exp2f(st[i]);

            // ---- pack, l via dot2, vf reads, PV MFMAs ----
            __builtin_amdgcn_s_setprio(1);
            {
                unsigned w0 = pkh(st[0], st[1]),   w1 = pkh(st[2], st[3]);
                unsigned w2 = pkh(st[4], st[5]),   w3 = pkh(st[6], st[7]);
                unsigned w4 = pkh(st[8], st[9]),   w5 = pkh(st[10], st[11]);
                unsigned w6 = pkh(st[12], st[13]), w7 = pkh(st[14], st[15]);
                la = sum2(w0, la); lb = sum2(w1, lb);
                la = sum2(w2, la); lb = sum2(w3, lb);
                la = sum2(w4, la); lb = sum2(w5, lb);
                la = sum2(w6, la); lb = sum2(w7, lb);
                f16x8 vf00 = *(const f16x8*)&vbase[(0 * 32 + lo) * 64 + (((kt * 4 + 0 + hw) ^ (lo & 7)) << 3)];
                f16x8 vf10 = *(const f16x8*)&vbase[(1 * 32 + lo) * 64 + (((kt * 4 + 0 + hw) ^ (lo & 7)) << 3)];
                {
                    unsigned a0 = w0, b0 = w2; plswap(a0, b0);
                    unsigned a1 = w1, b1 = w3; plswap(a1, b1);
                    u32x4 t_ = { a0, a1, b0, b1 };
                    f16x8 pb = __builtin_bit_cast(f16x8, t_);
                    ctx0 = mfma32(vf00, pb, ctx0);
                    ctx1 = mfma32(vf10, pb, ctx1);
                }
                f16x8 vf01 = *(const f16x8*)&vbase[(0 * 32 + lo) * 64 + (((kt * 4 + 2 + hw) ^ (lo & 7)) << 3)];
                f16x8 vf11 = *(const f16x8*)&vbase[(1 * 32 + lo) * 64 + (((kt * 4 + 2 + hw) ^ (lo & 7)) << 3)];
                {
                    unsigned a0 = w4, b0 = w6; plswap(a0, b0);
                    unsigned a1 = w5, b1 = w7; plswap(a1, b1);
                    u32x4 t_ = { a0, a1, b0, b1 };
                    f16x8 pb = __builtin_bit_cast(f16x8, t_);
                    ctx0 = mfma32(vf01, pb, ctx0);
                    ctx1 = mfma32(vf11, pb, ctx1);
                }
            }
            __builtin_amdgcn_s_setprio(0);
        }

        bc = (bc + 1 == NBUF) ? 0 : bc + 1;
    }
#undef STAGE

    __syncthreads();   // all waves done with smem tiles before transpose reuse

    // ---- epilogue: combine l halves (deferred), divide, transpose, store ----
    float lown = la + lb;
    float2 lp = plswapf(lown);
    float rl = 1.0f / (lp.x + lp.y);
    f16* tbp = &smem[0][0][0] + wv * (32 * 66);
#pragma unroll
    for (int u = 0; u < 8; ++u) {
        int d0 = 2 * (u & 1) + 8 * (u >> 1) + 4 * hw;
        unsigned pw0 = pkh(ctx0[2 * u] * rl, ctx0[2 * u + 1] * rl);
        unsigned pw1 = pkh(ctx1[2 * u] * rl, ctx1[2 * u + 1] * rl);
        *(unsigned*)&tbp[lo * 66 + d0] = pw0;
        *(unsigned*)&tbp[lo * 66 + 32 + d0] = pw1;
    }
    __syncthreads();
#pragma unroll
    for (int it = 0; it < 4; ++it) {
        int r = it * 8 + (lane >> 3);
        const unsigned* src = (const unsigned*)(tbp + r * 66);
        int cc = (lane & 7) * 4;
        u32x4 t = { src[cc], src[cc + 1], src[cc + 2], src[cc + 3] };
        f16x8 vvv = __builtin_bit_cast(f16x8, t);
        *(f16x8*)(out16 + ((size_t)(b * SEQ) + q0 + r) * DM + hd * 64 + (lane & 7) * 8) = vvv;
    }
}

// ---------------- in-place LayerNorm ----------------
__global__ __launch_bounds__(256) void ln_kernel(
    float* __restrict__ x, const float* __restrict__ gamma,
    const float* __restrict__ beta) {
    const int lane = threadIdx.x & 63;
    const int wave = threadIdx.x >> 6;
    const int row = blockIdx.x * 4 + wave;
    float* rp = x + (size_t)row * DM;

    float4 v[4];
#pragma unroll
    for (int j = 0; j < 4; ++j) v[j] = ((const float4*)rp)[lane + 64 * j];

    float sum = 0.f;
#pragma unroll
    for (int j = 0; j < 4; ++j) sum += v[j].x + v[j].y + v[j].z + v[j].w;
#pragma unroll
    for (int off = 1; off < 64; off <<= 1) sum += __shfl_xor(sum, off);
    float mean = sum * (1.f / DM);

    float vs = 0.f;
#pragma unroll
    for (int j = 0; j < 4; ++j) {
        float dx = v[j].x - mean, dy = v[j].y - mean, dz = v[j].z - mean, dw = v[j].w - mean;
        vs += dx * dx + dy * dy + dz * dz + dw * dw;
    }
#pragma unroll
    for (int off = 1; off < 64; off <<= 1) vs += __shfl_xor(vs, off);
    float rstd = rsqrtf(vs * (1.f / DM) + 1e-5f);

#pragma unroll
    for (int j = 0; j < 4; ++j) {
        int idx = lane + 64 * j;
        float4 g = ((const float4*)gamma)[idx];
        float4 bt = ((const float4*)beta)[idx];
        float4 o;
        o.x = (v[j].x - mean) * rstd * g.x + bt.x;
        o.y = (v[j].y - mean) * rstd * g.y + bt.y;
        o.z = (v[j].z - mean) * rstd * g.z + bt.z;
        o.w = (v[j].w - mean) * rstd * g.w + bt.w;
        ((float4*)rp)[idx] = o;
    }
}

extern "C" void kernel_launch(void* const* d_in, const int* in_sizes, int n_in,
                              void* d_out, int out_size, void* d_ws, size_t ws_size,
                              hipStream_t stream) {
    const float* Q    = (const float*)d_in[0];
    const float* K    = (const float*)d_in[1];
    const float* V    = (const float*)d_in[2];
    const int*   mask = (const int*)d_in[3];
    const float* Wq   = (const float*)d_in[4];
    const float* bq   = (const float*)d_in[5];
    const float* Wk   = (const float*)d_in[6];
    const float* bk   = (const float*)d_in[7];
    const float* Wv   = (const float*)d_in[8];
    const float* bv   = (const float*)d_in[9];
    const float* Wo   = (const float*)d_in[10];
    const float* bo   = (const float*)d_in[11];
    const float* gamma = (const float*)d_in[12];
    const float* beta  = (const float*)d_in[13];
    float* out = (float*)d_out;

    char* ws = (char*)d_ws;
    const size_t MB = 1024 * 1024;
    f16* wq16 = (f16*)(ws + 0 * MB);
    f16* wk16 = (f16*)(ws + 2 * MB);
    f16* wv16 = (f16*)(ws + 4 * MB);
    f16* wo16 = (f16*)(ws + 6 * MB);
    f16* c16  = (f16*)(ws + 8 * MB);
    f16* q16  = (f16*)(ws + 24 * MB);
    f16* k16  = (f16*)(ws + 40 * MB);
    f16* v16t = (f16*)(ws + 56 * MB);  // total 72 MB

    // packed mask lives in the tail of d_out; oproj overwrites all of out later
    unsigned* pm = (unsigned*)((char*)d_out + (size_t)out_size * 4 - 4096);

    cvt_weights<<<dim3(DM * DM / (256 * 4)), dim3(256), 0, stream>>>(
        Wq, Wk, Wv, Wo, wq16, wk16, wv16, wo16, mask, pm);

    const float qscale = 0.125f * 1.44269504f;   // 1/sqrt(DH) * log2(e)

    gemm_proj3<<<dim3(ROWS / BM, DM / BN, 3), dim3(256), 0, stream>>>(
        Q, K, V, wq16, wk16, wv16, bq, bk, bv, q16, k16, v16t, qscale);

    attn_kernel<<<dim3(SEQ / 128, BB * NH), dim3(256), 0, stream>>>(
        q16, k16, v16t, pm, c16);

    gemm_oproj<<<dim3(ROWS / BM, DM / BN), dim3(256), 0, stream>>>(
        c16, wo16, bo, Q, out);

    ln_kernel<<<dim3(ROWS / 4), dim3(256), 0, stream>>>(out, gamma, beta);
}